// Round 1
// baseline (356.212 us; speedup 1.0000x reference)
//
#include <hip/hip_runtime.h>
#include <math.h>

// GammaContrastReconLoss: total = 0.5*supcon + 0.5*masked_mse
// B=2048, D=1024, S=128, H=512 (derived from in_sizes; tile code assumes B%64==0, D%32==0, H%4==0)

#define TEMP_INV 10.0f   // 1/TEMP
#define GAMMA 0.5f

__device__ __forceinline__ float blockReduceSum(float v) {
    __shared__ float red[8];
    #pragma unroll
    for (int off = 32; off > 0; off >>= 1) v += __shfl_down(v, off, 64);
    int lane = threadIdx.x & 63, wid = threadIdx.x >> 6;
    __syncthreads();                 // safe reuse across sequential calls
    if (lane == 0) red[wid] = v;
    __syncthreads();
    float r = 0.f;
    if (threadIdx.x == 0) {
        int nw = (blockDim.x + 63) >> 6;
        for (int w = 0; w < nw; ++w) r += red[w];
    }
    return r;  // valid in thread 0 only
}

// ---- 1. per-row inverse norms of latents -------------------------------
__global__ void norm_inv_kernel(const float* __restrict__ x, float* __restrict__ inv, int D) {
    int row = blockIdx.x;
    const float4* xr = (const float4*)(x + (size_t)row * D);
    int n4 = D >> 2;
    float s = 0.f;
    for (int i = threadIdx.x; i < n4; i += blockDim.x) {
        float4 v = xr[i];
        s += v.x * v.x + v.y * v.y + v.z * v.z + v.w * v.w;
    }
    float tot = blockReduceSum(s);
    if (threadIdx.x == 0) inv[row] = 1.0f / fmaxf(sqrtf(tot), 1e-12f);
}

// ---- 2. contrast: tiled fp32 self-GEMM + fused per-row reductions ------
// 64x64 output tile per block, 256 threads, each thread 4x4 micro-tile.
__global__ void contrast_kernel(const float* __restrict__ A, const float* __restrict__ inv,
                                const int* __restrict__ labels,
                                float* __restrict__ denomAcc, float* __restrict__ posAcc,
                                float* __restrict__ cntAcc, int B, int D) {
    constexpr int BM = 64, BN = 64, BK = 32, PAD = 4;
    __shared__ float As[BK][BM + PAD];
    __shared__ float Bs[BK][BN + PAD];

    int tid = threadIdx.x;
    int tx = tid & 15, ty = tid >> 4;
    int brow = blockIdx.y * BM;
    int bcol = blockIdx.x * BN;

    float acc[4][4] = {};

    for (int k0 = 0; k0 < D; k0 += BK) {
        // load A-tile (rows brow..+63) and B-tile (rows bcol..+63), K-major in LDS
        #pragma unroll
        for (int p = tid; p < (BM * BK) / 4; p += 256) {
            int r = p >> 3, c4 = p & 7;
            float4 v = *(const float4*)(A + (size_t)(brow + r) * D + k0 + c4 * 4);
            As[c4 * 4 + 0][r] = v.x; As[c4 * 4 + 1][r] = v.y;
            As[c4 * 4 + 2][r] = v.z; As[c4 * 4 + 3][r] = v.w;
            float4 w = *(const float4*)(A + (size_t)(bcol + r) * D + k0 + c4 * 4);
            Bs[c4 * 4 + 0][r] = w.x; Bs[c4 * 4 + 1][r] = w.y;
            Bs[c4 * 4 + 2][r] = w.z; Bs[c4 * 4 + 3][r] = w.w;
        }
        __syncthreads();
        #pragma unroll
        for (int k = 0; k < BK; ++k) {
            float4 av = *(const float4*)&As[k][ty * 4];
            float4 bv = *(const float4*)&Bs[k][tx * 4];
            float a[4] = {av.x, av.y, av.z, av.w};
            float b[4] = {bv.x, bv.y, bv.z, bv.w};
            #pragma unroll
            for (int i = 0; i < 4; ++i)
                #pragma unroll
                for (int j = 0; j < 4; ++j)
                    acc[i][j] = fmaf(a[i], b[j], acc[i][j]);
        }
        __syncthreads();
    }

    // epilogue: sim = dot * inv_i * inv_j / TEMP; fused row reductions
    int gr[4], gc[4], lr[4], lc[4];
    float invr[4], invc[4];
    #pragma unroll
    for (int i = 0; i < 4; ++i) {
        gr[i] = brow + ty * 4 + i;  gc[i] = bcol + tx * 4 + i;
        invr[i] = inv[gr[i]];       invc[i] = inv[gc[i]];
        lr[i] = labels[gr[i]];      lc[i] = labels[gc[i]];
    }
    float dsum[4] = {}, psum[4] = {}, pcnt[4] = {};
    #pragma unroll
    for (int i = 0; i < 4; ++i) {
        #pragma unroll
        for (int j = 0; j < 4; ++j) {
            if (gr[i] == gc[j]) continue;               // eye exclusion
            float sim = acc[i][j] * invr[i] * invc[j] * TEMP_INV;
            dsum[i] += __expf(sim - TEMP_INV);          // exp(sim - 10), sim<=10
            if (lr[i] == lc[j]) { psum[i] += sim; pcnt[i] += 1.f; }
        }
    }
    // reduce across the 16 column-threads of each row group (lanes are consecutive)
    #pragma unroll
    for (int i = 0; i < 4; ++i) {
        float d = dsum[i], p = psum[i], c = pcnt[i];
        #pragma unroll
        for (int off = 8; off > 0; off >>= 1) {
            d += __shfl_down(d, off, 16);
            p += __shfl_down(p, off, 16);
            c += __shfl_down(c, off, 16);
        }
        if (tx == 0) {
            atomicAdd(&denomAcc[gr[i]], d);
            atomicAdd(&posAcc[gr[i]], p);
            atomicAdd(&cntAcc[gr[i]], c);
        }
    }
}

// ---- 3. mask sum --------------------------------------------------------
__global__ void masksum_kernel(const float4* __restrict__ mask4, float* __restrict__ acc, unsigned n4) {
    unsigned i = blockIdx.x * blockDim.x + threadIdx.x;
    unsigned stride = gridDim.x * blockDim.x;
    float local = 0.f;
    for (; i < n4; i += stride) {
        float4 m = mask4[i];
        local += m.x + m.y + m.z + m.w;
    }
    float tot = blockReduceSum(local);
    if (threadIdx.x == 0) atomicAdd(acc, tot);
}

// ---- 4. recon: sum over (b,s,h) of (p-t)^2 * mask[b,s] ------------------
__global__ void recon_kernel(const float4* __restrict__ p, const float4* __restrict__ t,
                             const float* __restrict__ mask, float* __restrict__ acc,
                             unsigned n4, unsigned h4) {
    unsigned i = blockIdx.x * blockDim.x + threadIdx.x;
    unsigned stride = gridDim.x * blockDim.x;
    float local = 0.f;
    for (; i < n4; i += stride) {
        float4 a = p[i], b = t[i];
        float m = mask[i / h4];
        float dx = a.x - b.x, dy = a.y - b.y, dz = a.z - b.z, dw = a.w - b.w;
        local += m * (dx * dx + dy * dy + dz * dz + dw * dw);
    }
    float tot = blockReduceSum(local);
    if (threadIdx.x == 0) atomicAdd(acc, tot);
}

// ---- 5. finalize ---------------------------------------------------------
__global__ void finalize_kernel(const float* __restrict__ denom, const float* __restrict__ pos,
                                const float* __restrict__ cnt, const float* __restrict__ racc,
                                const float* __restrict__ msum, float* __restrict__ out,
                                int B, float invH) {
    float lsum = 0.f, vcnt = 0.f;
    for (int r = threadIdx.x; r < B; r += blockDim.x) {
        float c = cnt[r];
        if (c > 0.5f) {
            float ld = logf(denom[r]) + TEMP_INV;     // log(sum exp(sim-10)) + 10
            lsum += ld - pos[r] / c;                  // c >= 1 when valid
            vcnt += 1.f;
        }
    }
    lsum = blockReduceSum(lsum);
    vcnt = blockReduceSum(vcnt);
    if (threadIdx.x == 0) {
        float contrast = lsum / fmaxf(vcnt, 1.f);
        float recon = racc[0] * invH / fmaxf(msum[0], 1.f);
        out[0] = GAMMA * contrast + (1.f - GAMMA) * recon;
        out[1] = contrast;
        out[2] = recon;
    }
}

extern "C" void kernel_launch(void* const* d_in, const int* in_sizes, int n_in,
                              void* d_out, int out_size, void* d_ws, size_t ws_size,
                              hipStream_t stream) {
    const float* latents = (const float*)d_in[0];
    const float* recon   = (const float*)d_in[1];
    const float* target  = (const float*)d_in[2];
    const float* mask    = (const float*)d_in[3];
    const int*   labels  = (const int*)d_in[4];
    float* out = (float*)d_out;
    float* ws  = (float*)d_ws;

    int B = in_sizes[4];
    int D = in_sizes[0] / B;
    int S = in_sizes[3] / B;
    int H = (in_sizes[1] / B) / S;

    // workspace layout (floats): denom[B] | pos[B] | cnt[B] | racc | msum | pad | inv[B]
    float* denom = ws;
    float* pos   = ws + B;
    float* cnt   = ws + 2 * B;
    float* racc  = ws + 3 * B;
    float* msum  = ws + 3 * B + 1;
    float* inv   = ws + 3 * B + 64;

    hipMemsetAsync(d_ws, 0, (size_t)(3 * B + 64) * sizeof(float), stream);

    norm_inv_kernel<<<B, 256, 0, stream>>>(latents, inv, D);

    dim3 cgrid(B / 64, B / 64);
    contrast_kernel<<<cgrid, 256, 0, stream>>>(latents, inv, labels, denom, pos, cnt, B, D);

    unsigned nBS4 = (unsigned)(B * S) / 4;
    masksum_kernel<<<256, 256, 0, stream>>>((const float4*)mask, msum, nBS4);

    unsigned n4 = (unsigned)B * (unsigned)S * (unsigned)(H / 4);
    recon_kernel<<<4096, 256, 0, stream>>>((const float4*)recon, (const float4*)target,
                                           mask, racc, n4, (unsigned)(H / 4));

    finalize_kernel<<<1, 256, 0, stream>>>(denom, pos, cnt, racc, msum, out, B, 1.0f / H);
}

// Round 2
// 252.963 us; speedup vs baseline: 1.4082x; 1.4082x over previous
//
#include <hip/hip_runtime.h>
#include <math.h>

// GammaContrastReconLoss: total = 0.5*supcon + 0.5*masked_mse
// B=2048, D=1024, S=128, H=512. Assumes B%128==0, D%64==0, H%4==0.
//
// Pipeline: norm_convert (latents -> unit-norm bf16 in ws)
//        -> contrast_mfma (bf16 MFMA self-GEMM, fused row reductions)
//        -> masksum, recon (streaming), finalize.

#define TEMP_INV 10.0f   // 1/TEMP
#define GAMMA 0.5f

using short8 = __attribute__((ext_vector_type(8))) short;  // 8 bf16 (4 VGPRs)
using f32x4  = __attribute__((ext_vector_type(4))) float;  // MFMA acc

__device__ __forceinline__ float blockReduceSum(float v) {
    __shared__ float red[8];
    #pragma unroll
    for (int off = 32; off > 0; off >>= 1) v += __shfl_down(v, off, 64);
    int lane = threadIdx.x & 63, wid = threadIdx.x >> 6;
    __syncthreads();
    if (lane == 0) red[wid] = v;
    __syncthreads();
    float r = 0.f;
    if (threadIdx.x == 0) {
        int nw = (blockDim.x + 63) >> 6;
        for (int w = 0; w < nw; ++w) r += red[w];
    }
    return r;  // valid in thread 0 only
}

__device__ __forceinline__ unsigned short f2bf(float f) {  // RNE f32->bf16 bits
    unsigned u = __float_as_uint(f);
    unsigned r = (u + 0x7FFFu + ((u >> 16) & 1u)) >> 16;
    return (unsigned short)r;
}

// ---- 1. row-normalize latents and convert to bf16 ----------------------
__global__ void norm_convert_kernel(const float* __restrict__ x,
                                    unsigned short* __restrict__ nbf, int D) {
    int row = blockIdx.x;
    const float4* xr = (const float4*)(x + (size_t)row * D);
    unsigned short* nr = nbf + (size_t)row * D;
    int n4 = D >> 2;
    float s = 0.f;
    for (int i = threadIdx.x; i < n4; i += blockDim.x) {
        float4 v = xr[i];
        s += v.x * v.x + v.y * v.y + v.z * v.z + v.w * v.w;
    }
    float tot = blockReduceSum(s);
    __shared__ float s_inv;
    if (threadIdx.x == 0) s_inv = 1.0f / fmaxf(sqrtf(tot), 1e-12f);
    __syncthreads();
    float inv = s_inv;
    for (int i = threadIdx.x; i < n4; i += blockDim.x) {
        float4 v = xr[i];
        ushort4 o;
        o.x = f2bf(v.x * inv); o.y = f2bf(v.y * inv);
        o.z = f2bf(v.z * inv); o.w = f2bf(v.w * inv);
        *(ushort4*)(nr + i * 4) = o;
    }
}

// ---- 2. contrast: bf16 MFMA self-GEMM + fused per-row reductions --------
// 128x128 tile / block, 256 threads = 4 waves (2x2), wave = 64x64 (4x4 frags
// of mfma_f32_16x16x32_bf16). LDS tiles [128 rows][64 bf16] with T2 XOR
// swizzle (unit ^= row&7) to kill the 128B-row bank conflict on ds_read_b128.
__global__ void contrast_mfma_kernel(const short* __restrict__ nbf,
                                     const int* __restrict__ labels,
                                     float* __restrict__ denomAcc,
                                     float* __restrict__ posAcc,
                                     float* __restrict__ cntAcc, int B, int D) {
    constexpr int BM = 128, BK = 64;
    __shared__ short As[BM * BK];
    __shared__ short Bs[BM * BK];

    const int tid  = threadIdx.x;
    const int lane = tid & 63;
    const int w    = tid >> 6;
    const int wr   = w >> 1, wc = w & 1;
    const int brow = blockIdx.y * BM;
    const int bcol = blockIdx.x * BM;
    const int g    = lane >> 4, l15 = lane & 15;

    f32x4 acc[4][4] = {};

    for (int k0 = 0; k0 < D; k0 += BK) {
        // stage 128x64 bf16 tiles; write-side swizzle: 16B unit cu ^= (row&7)
        #pragma unroll
        for (int i = 0; i < 4; ++i) {
            int chunk = i * 256 + tid;        // 0..1023
            int r  = chunk >> 3;              // 0..127
            int cu = chunk & 7;               // 16B unit in row
            int su = cu ^ (r & 7);
            uint4 va = *(const uint4*)(nbf + (size_t)(brow + r) * D + k0 + cu * 8);
            *(uint4*)(As + r * BK + su * 8) = va;
            uint4 vb = *(const uint4*)(nbf + (size_t)(bcol + r) * D + k0 + cu * 8);
            *(uint4*)(Bs + r * BK + su * 8) = vb;
        }
        __syncthreads();

        short8 a[4][2], b[4][2];
        #pragma unroll
        for (int mi = 0; mi < 4; ++mi) {
            int ra = wr * 64 + mi * 16 + l15;
            int rb = wc * 64 + mi * 16 + l15;
            #pragma unroll
            for (int ks = 0; ks < 2; ++ks) {
                int ua = (ks * 4 + g) ^ (ra & 7);
                a[mi][ks] = *(const short8*)(As + ra * BK + ua * 8);
                int ub = (ks * 4 + g) ^ (rb & 7);
                b[mi][ks] = *(const short8*)(Bs + rb * BK + ub * 8);
            }
        }
        #pragma unroll
        for (int ks = 0; ks < 2; ++ks)
            #pragma unroll
            for (int mi = 0; mi < 4; ++mi)
                #pragma unroll
                for (int ni = 0; ni < 4; ++ni)
                    acc[mi][ni] = __builtin_amdgcn_mfma_f32_16x16x32_bf16(
                        a[mi][ks], b[ni][ks], acc[mi][ni], 0, 0, 0);
        __syncthreads();
    }

    // epilogue: sim = cos * 10; fused per-row reductions (sim symmetric, so
    // any row/col transposition in the C layout is harmless).
    int lc[4], gcv[4];
    #pragma unroll
    for (int ni = 0; ni < 4; ++ni) {
        gcv[ni] = bcol + wc * 64 + ni * 16 + l15;
        lc[ni]  = labels[gcv[ni]];
    }
    #pragma unroll
    for (int mi = 0; mi < 4; ++mi) {
        #pragma unroll
        for (int r = 0; r < 4; ++r) {
            int R  = brow + wr * 64 + mi * 16 + g * 4 + r;
            int lr = labels[R];
            float d = 0.f, p = 0.f, c = 0.f;
            #pragma unroll
            for (int ni = 0; ni < 4; ++ni) {
                float sim = acc[mi][ni][r] * TEMP_INV;
                if (R != gcv[ni]) {
                    d += __expf(sim - TEMP_INV);     // exp(sim-10), sim<=10
                    if (lr == lc[ni]) { p += sim; c += 1.f; }
                }
            }
            #pragma unroll
            for (int off = 8; off > 0; off >>= 1) {
                d += __shfl_down(d, off, 16);
                p += __shfl_down(p, off, 16);
                c += __shfl_down(c, off, 16);
            }
            if (l15 == 0) {
                atomicAdd(&denomAcc[R], d);
                atomicAdd(&posAcc[R], p);
                atomicAdd(&cntAcc[R], c);
            }
        }
    }
}

// ---- 3. mask sum --------------------------------------------------------
__global__ void masksum_kernel(const float4* __restrict__ mask4, float* __restrict__ acc, unsigned n4) {
    unsigned i = blockIdx.x * blockDim.x + threadIdx.x;
    unsigned stride = gridDim.x * blockDim.x;
    float local = 0.f;
    for (; i < n4; i += stride) {
        float4 m = mask4[i];
        local += m.x + m.y + m.z + m.w;
    }
    float tot = blockReduceSum(local);
    if (threadIdx.x == 0) atomicAdd(acc, tot);
}

// ---- 4. recon: sum over (b,s,h) of (p-t)^2 * mask[b,s] ------------------
__global__ void recon_kernel(const float4* __restrict__ p, const float4* __restrict__ t,
                             const float* __restrict__ mask, float* __restrict__ acc,
                             unsigned n4, unsigned h4) {
    unsigned i = blockIdx.x * blockDim.x + threadIdx.x;
    unsigned stride = gridDim.x * blockDim.x;
    float local = 0.f;
    for (; i < n4; i += stride) {
        float4 a = p[i], b = t[i];
        float m = mask[i / h4];
        float dx = a.x - b.x, dy = a.y - b.y, dz = a.z - b.z, dw = a.w - b.w;
        local += m * (dx * dx + dy * dy + dz * dz + dw * dw);
    }
    float tot = blockReduceSum(local);
    if (threadIdx.x == 0) atomicAdd(acc, tot);
}

// ---- 5. finalize ---------------------------------------------------------
__global__ void finalize_kernel(const float* __restrict__ denom, const float* __restrict__ pos,
                                const float* __restrict__ cnt, const float* __restrict__ racc,
                                const float* __restrict__ msum, float* __restrict__ out,
                                int B, float invH) {
    float lsum = 0.f, vcnt = 0.f;
    for (int r = threadIdx.x; r < B; r += blockDim.x) {
        float c = cnt[r];
        if (c > 0.5f) {
            float ld = logf(denom[r]) + TEMP_INV;     // log(sum exp(sim-10)) + 10
            lsum += ld - pos[r] / c;
            vcnt += 1.f;
        }
    }
    lsum = blockReduceSum(lsum);
    vcnt = blockReduceSum(vcnt);
    if (threadIdx.x == 0) {
        float contrast = lsum / fmaxf(vcnt, 1.f);
        float recon = racc[0] * invH / fmaxf(msum[0], 1.f);
        out[0] = GAMMA * contrast + (1.f - GAMMA) * recon;
        out[1] = contrast;
        out[2] = recon;
    }
}

extern "C" void kernel_launch(void* const* d_in, const int* in_sizes, int n_in,
                              void* d_out, int out_size, void* d_ws, size_t ws_size,
                              hipStream_t stream) {
    const float* latents = (const float*)d_in[0];
    const float* recon   = (const float*)d_in[1];
    const float* target  = (const float*)d_in[2];
    const float* mask    = (const float*)d_in[3];
    const int*   labels  = (const int*)d_in[4];
    float* out = (float*)d_out;
    float* ws  = (float*)d_ws;

    int B = in_sizes[4];
    int D = in_sizes[0] / B;
    int S = in_sizes[3] / B;
    int H = (in_sizes[1] / B) / S;

    // ws floats: denom[B] | pos[B] | cnt[B] | racc | msum | pad.. | nbf[B*D bf16]
    float* denom = ws;
    float* pos   = ws + B;
    float* cnt   = ws + 2 * B;
    float* racc  = ws + 3 * B;
    float* msum  = ws + 3 * B + 1;
    unsigned short* nbf = (unsigned short*)(ws + 3 * B + 64);  // 16B-aligned

    hipMemsetAsync(d_ws, 0, (size_t)(3 * B + 64) * sizeof(float), stream);

    norm_convert_kernel<<<B, 256, 0, stream>>>(latents, nbf, D);

    dim3 cgrid(B / 128, B / 128);
    contrast_mfma_kernel<<<cgrid, 256, 0, stream>>>((const short*)nbf, labels,
                                                    denom, pos, cnt, B, D);

    unsigned nBS4 = (unsigned)(B * S) / 4;
    masksum_kernel<<<256, 256, 0, stream>>>((const float4*)mask, msum, nBS4);

    unsigned n4 = (unsigned)B * (unsigned)S * (unsigned)(H / 4);
    recon_kernel<<<4096, 256, 0, stream>>>((const float4*)recon, (const float4*)target,
                                           mask, racc, n4, (unsigned)(H / 4));

    finalize_kernel<<<1, 256, 0, stream>>>(denom, pos, cnt, racc, msum, out, B, 1.0f / H);
}

// Round 3
// 228.229 us; speedup vs baseline: 1.5608x; 1.1084x over previous
//
#include <hip/hip_runtime.h>
#include <math.h>

// GammaContrastReconLoss: total = 0.5*supcon + 0.5*masked_mse
// B=2048, D=1024, S=128, H=512. Assumes B%128==0, D%64==0, H%4==0, (H/4) pow2.
//
// Pipeline: memset(ws header) -> norm_convert -> FUSED{contrast MFMA tiles |
// recon stream | masksum} (block-role partition, contrast hides under the
// BW-bound recon stream) -> finalize.

#define TEMP_INV 10.0f   // 1/TEMP
#define GAMMA 0.5f

using short8 = __attribute__((ext_vector_type(8))) short;  // 8 bf16 (4 VGPRs)
using f32x4  = __attribute__((ext_vector_type(4))) float;  // MFMA acc / vec load

__device__ __forceinline__ float blockReduceSum(float v) {
    __shared__ float red[8];
    #pragma unroll
    for (int off = 32; off > 0; off >>= 1) v += __shfl_down(v, off, 64);
    int lane = threadIdx.x & 63, wid = threadIdx.x >> 6;
    __syncthreads();
    if (lane == 0) red[wid] = v;
    __syncthreads();
    float r = 0.f;
    if (threadIdx.x == 0) {
        int nw = (blockDim.x + 63) >> 6;
        for (int w = 0; w < nw; ++w) r += red[w];
    }
    return r;  // valid in thread 0 only
}

__device__ __forceinline__ unsigned short f2bf(float f) {  // RNE f32->bf16 bits
    unsigned u = __float_as_uint(f);
    unsigned r = (u + 0x7FFFu + ((u >> 16) & 1u)) >> 16;
    return (unsigned short)r;
}

// ---- 1. row-normalize latents and convert to bf16 ----------------------
__global__ void norm_convert_kernel(const float* __restrict__ x,
                                    unsigned short* __restrict__ nbf, int D) {
    int row = blockIdx.x;
    const float4* xr = (const float4*)(x + (size_t)row * D);
    unsigned short* nr = nbf + (size_t)row * D;
    int n4 = D >> 2;
    float s = 0.f;
    for (int i = threadIdx.x; i < n4; i += blockDim.x) {
        float4 v = xr[i];
        s += v.x * v.x + v.y * v.y + v.z * v.z + v.w * v.w;
    }
    float tot = blockReduceSum(s);
    __shared__ float s_inv;
    if (threadIdx.x == 0) s_inv = 1.0f / fmaxf(sqrtf(tot), 1e-12f);
    __syncthreads();
    float inv = s_inv;
    for (int i = threadIdx.x; i < n4; i += blockDim.x) {
        float4 v = xr[i];
        ushort4 o;
        o.x = f2bf(v.x * inv); o.y = f2bf(v.y * inv);
        o.z = f2bf(v.z * inv); o.w = f2bf(v.w * inv);
        *(ushort4*)(nr + i * 4) = o;
    }
}

// ---- 2. FUSED: contrast MFMA | recon stream | masksum -------------------
// Block roles by blockIdx.x:
//   [0, NC)          : 128x128 bf16 MFMA contrast tiles (NC = (B/128)^2)
//   [NC, NC+NR)      : recon masked-MSE grid-stride stream (NT loads)
//   [NC+NR, +NM)     : mask sum
// 32 KB static LDS (contrast tiles) caps co-residency at 5 blocks/CU; one
// contrast block + 4 recon blocks co-reside, so the ~25 us of MFMA work
// hides under the ~175 us BW-bound stream.
__launch_bounds__(256)
__global__ void fused_kernel(const short* __restrict__ nbf,
                             const int* __restrict__ labels,
                             const f32x4* __restrict__ p4,
                             const f32x4* __restrict__ t4,
                             const float* __restrict__ mask,
                             float* __restrict__ denomAcc,
                             float* __restrict__ posAcc,
                             float* __restrict__ cntAcc,
                             float* __restrict__ racc,
                             float* __restrict__ msum,
                             int B, int D,
                             unsigned n4, int shiftH4, unsigned nBS4,
                             int nbx, int NC, int NR) {
    constexpr int BM = 128, BK = 64;
    __shared__ short lds[2 * BM * BK];      // 32 KB, contrast branch only
    short* As = lds;
    short* Bs = lds + BM * BK;

    const int tid = threadIdx.x;
    const int role = blockIdx.x;

    if (role < NC) {
        // ---------------- contrast tile ----------------
        const int lane = tid & 63;
        const int w    = tid >> 6;
        const int wr   = w >> 1, wc = w & 1;
        const int brow = (role / nbx) * BM;
        const int bcol = (role % nbx) * BM;
        const int g    = lane >> 4, l15 = lane & 15;

        f32x4 acc[4][4] = {};

        for (int k0 = 0; k0 < D; k0 += BK) {
            // stage 128x64 bf16 tiles; write-side swizzle: 16B unit ^= (row&7)
            #pragma unroll
            for (int i = 0; i < 4; ++i) {
                int chunk = i * 256 + tid;        // 0..1023
                int r  = chunk >> 3;              // 0..127
                int cu = chunk & 7;               // 16B unit in row
                int su = cu ^ (r & 7);
                uint4 va = *(const uint4*)(nbf + (size_t)(brow + r) * D + k0 + cu * 8);
                *(uint4*)(As + r * BK + su * 8) = va;
                uint4 vb = *(const uint4*)(nbf + (size_t)(bcol + r) * D + k0 + cu * 8);
                *(uint4*)(Bs + r * BK + su * 8) = vb;
            }
            __syncthreads();

            short8 a[4][2], b[4][2];
            #pragma unroll
            for (int mi = 0; mi < 4; ++mi) {
                int ra = wr * 64 + mi * 16 + l15;
                int rb = wc * 64 + mi * 16 + l15;
                #pragma unroll
                for (int ks = 0; ks < 2; ++ks) {
                    int ua = (ks * 4 + g) ^ (ra & 7);
                    a[mi][ks] = *(const short8*)(As + ra * BK + ua * 8);
                    int ub = (ks * 4 + g) ^ (rb & 7);
                    b[mi][ks] = *(const short8*)(Bs + rb * BK + ub * 8);
                }
            }
            #pragma unroll
            for (int ks = 0; ks < 2; ++ks)
                #pragma unroll
                for (int mi = 0; mi < 4; ++mi)
                    #pragma unroll
                    for (int ni = 0; ni < 4; ++ni)
                        acc[mi][ni] = __builtin_amdgcn_mfma_f32_16x16x32_bf16(
                            a[mi][ks], b[ni][ks], acc[mi][ni], 0, 0, 0);
            __syncthreads();
        }

        // epilogue: sim = cos * 10; fused per-row reductions
        int lc[4], gcv[4];
        #pragma unroll
        for (int ni = 0; ni < 4; ++ni) {
            gcv[ni] = bcol + wc * 64 + ni * 16 + l15;
            lc[ni]  = labels[gcv[ni]];
        }
        #pragma unroll
        for (int mi = 0; mi < 4; ++mi) {
            #pragma unroll
            for (int r = 0; r < 4; ++r) {
                int R  = brow + wr * 64 + mi * 16 + g * 4 + r;
                int lr = labels[R];
                float d = 0.f, p = 0.f, c = 0.f;
                #pragma unroll
                for (int ni = 0; ni < 4; ++ni) {
                    float sim = acc[mi][ni][r] * TEMP_INV;
                    if (R != gcv[ni]) {
                        d += __expf(sim - TEMP_INV);     // exp(sim-10), sim<=10
                        if (lr == lc[ni]) { p += sim; c += 1.f; }
                    }
                }
                #pragma unroll
                for (int off = 8; off > 0; off >>= 1) {
                    d += __shfl_down(d, off, 16);
                    p += __shfl_down(p, off, 16);
                    c += __shfl_down(c, off, 16);
                }
                if (l15 == 0) {
                    atomicAdd(&denomAcc[R], d);
                    atomicAdd(&posAcc[R], p);
                    atomicAdd(&cntAcc[R], c);
                }
            }
        }
    } else if (role < NC + NR) {
        // ---------------- recon stream ----------------
        unsigned i = (unsigned)(role - NC) * blockDim.x + tid;
        unsigned stride = (unsigned)NR * blockDim.x;
        float local = 0.f;
        for (; i < n4; i += stride) {
            f32x4 a = __builtin_nontemporal_load(&p4[i]);
            f32x4 b = __builtin_nontemporal_load(&t4[i]);
            float m = mask[i >> shiftH4];
            f32x4 dfl = a - b;
            local += m * (dfl[0] * dfl[0] + dfl[1] * dfl[1] +
                          dfl[2] * dfl[2] + dfl[3] * dfl[3]);
        }
        float tot = blockReduceSum(local);
        if (tid == 0) atomicAdd(racc, tot);
    } else {
        // ---------------- mask sum ----------------
        int nm = gridDim.x - NC - NR;
        unsigned i = (unsigned)(role - NC - NR) * blockDim.x + tid;
        unsigned stride = (unsigned)nm * blockDim.x;
        float local = 0.f;
        for (; i < nBS4; i += stride) {
            f32x4 m = *(const f32x4*)(mask + 4 * (size_t)i);
            local += m[0] + m[1] + m[2] + m[3];
        }
        float tot = blockReduceSum(local);
        if (tid == 0) atomicAdd(msum, tot);
    }
}

// ---- 3. finalize ---------------------------------------------------------
__global__ void finalize_kernel(const float* __restrict__ denom, const float* __restrict__ pos,
                                const float* __restrict__ cnt, const float* __restrict__ racc,
                                const float* __restrict__ msum, float* __restrict__ out,
                                int B, float invH) {
    float lsum = 0.f, vcnt = 0.f;
    for (int r = threadIdx.x; r < B; r += blockDim.x) {
        float c = cnt[r];
        if (c > 0.5f) {
            float ld = logf(denom[r]) + TEMP_INV;     // log(sum exp(sim-10)) + 10
            lsum += ld - pos[r] / c;
            vcnt += 1.f;
        }
    }
    lsum = blockReduceSum(lsum);
    vcnt = blockReduceSum(vcnt);
    if (threadIdx.x == 0) {
        float contrast = lsum / fmaxf(vcnt, 1.f);
        float recon = racc[0] * invH / fmaxf(msum[0], 1.f);
        out[0] = GAMMA * contrast + (1.f - GAMMA) * recon;
        out[1] = contrast;
        out[2] = recon;
    }
}

extern "C" void kernel_launch(void* const* d_in, const int* in_sizes, int n_in,
                              void* d_out, int out_size, void* d_ws, size_t ws_size,
                              hipStream_t stream) {
    const float* latents = (const float*)d_in[0];
    const float* recon   = (const float*)d_in[1];
    const float* target  = (const float*)d_in[2];
    const float* mask    = (const float*)d_in[3];
    const int*   labels  = (const int*)d_in[4];
    float* out = (float*)d_out;
    float* ws  = (float*)d_ws;

    int B = in_sizes[4];
    int D = in_sizes[0] / B;
    int S = in_sizes[3] / B;
    int H = (in_sizes[1] / B) / S;

    // ws floats: denom[B] | pos[B] | cnt[B] | racc | msum | pad.. | nbf[B*D bf16]
    float* denom = ws;
    float* pos   = ws + B;
    float* cnt   = ws + 2 * B;
    float* racc  = ws + 3 * B;
    float* msum  = ws + 3 * B + 1;
    unsigned short* nbf = (unsigned short*)(ws + 3 * B + 64);  // 16B-aligned

    hipMemsetAsync(d_ws, 0, (size_t)(3 * B + 64) * sizeof(float), stream);

    norm_convert_kernel<<<B, 256, 0, stream>>>(latents, nbf, D);

    int nbx = B / 128;
    int NC = nbx * nbx;              // 256 contrast tiles
    int NR = 1536;                   // recon stream blocks
    int NM = 16;                     // masksum blocks
    unsigned n4 = (unsigned)B * (unsigned)S * (unsigned)(H / 4);
    unsigned nBS4 = (unsigned)(B * S) / 4;
    int shiftH4 = __builtin_ctz((unsigned)(H / 4));

    fused_kernel<<<NC + NR + NM, 256, 0, stream>>>(
        (const short*)nbf, labels, (const f32x4*)recon, (const f32x4*)target,
        mask, denom, pos, cnt, racc, msum,
        B, D, n4, shiftH4, nBS4, nbx, NC, NR);

    finalize_kernel<<<1, 256, 0, stream>>>(denom, pos, cnt, racc, msum, out, B, 1.0f / H);
}